// Round 14
// baseline (166.472 us; speedup 1.0000x reference)
//
#include <hip/hip_runtime.h>
#include <hip/hip_fp8.h>
#include <stdint.h>

// (B,T,E,H,D) = (2,2048,1024,16,64)
constexpr float INV_SCALE = 0.022097086912079608f;  // 1/sqrt(2048)
constexpr float LOG2E = 1.4426950408889634f;
constexpr float QSC = INV_SCALE * LOG2E;            // q pre-scale: softmax in exp2 domain

typedef __attribute__((ext_vector_type(8))) short bfrag;          // 8 bf16 (4 VGPR) MFMA frag
typedef __attribute__((ext_vector_type(4))) float facc;           // 4 f32 MFMA acc
typedef __attribute__((ext_vector_type(4))) unsigned short us4;   // 4 bf16 = 8B

#define MFMA(a, b, c) __builtin_amdgcn_mfma_f32_16x16x32_bf16((a), (b), (c), 0, 0, 0)
#define EXP2(x) __builtin_amdgcn_exp2f(x)

__device__ __forceinline__ unsigned short f2bh(float f) {        // f32 -> bf16 RNE
    union { float f; unsigned int u; } cv; cv.f = f;
    unsigned int u = cv.u;
    u += 0x7FFFu + ((u >> 16) & 1u);
    return (unsigned short)(u >> 16);
}
__device__ __forceinline__ float bh2f(unsigned short h) {
    union { unsigned int u; float f; } cv; cv.u = ((unsigned int)h) << 16;
    return cv.f;
}
__device__ __forceinline__ void gl_lds16(const unsigned short* g, unsigned short* lds) {
    // async 16B/lane global->LDS; dst is wave-uniform base, lane i lands at dst+16*i
    __builtin_amdgcn_global_load_lds(
        (const __attribute__((address_space(1))) unsigned int*)g,
        (__attribute__((address_space(3))) unsigned int*)lds, 16, 0, 0);
}
// 8 fp8(e4m3, x256) bytes -> bf16 frag (undo the 256x scale)
__device__ __forceinline__ bfrag f8frag(uint2 raw) {
    union { uint2 u; unsigned char b[8]; } cv; cv.u = raw;
    bfrag r;
    #pragma unroll
    for (int j = 0; j < 8; ++j) {
        const __hip_fp8_e4m3* t = reinterpret_cast<const __hip_fp8_e4m3*>(&cv.b[j]);
        r[j] = (short)f2bh((float)(*t) * 0.00390625f);
    }
    return r;
}
// one DPP max-reduce stage over the 16-lane row (pure VALU, no LDS)
template<int CTRL>
__device__ __forceinline__ float dppmax(float v) {
    int s = __builtin_amdgcn_update_dpp(0, __builtin_bit_cast(int, v), CTRL, 0xF, 0xF, true);
    return fmaxf(v, __builtin_bit_cast(float, s));
}
__device__ __forceinline__ float rowmax16(float v) {
    v = dppmax<0xB1>(v);    // quad_perm [1,0,3,2]  (xor 1)
    v = dppmax<0x4E>(v);    // quad_perm [2,3,0,1]  (xor 2)
    v = dppmax<0x141>(v);   // row_half_mirror      (covers xor 4)
    v = dppmax<0x140>(v);   // row_mirror           (covers xor 8)
    return v;
}

// ---------------------------------------------------------------------------
// prep_all: ONE launch for all preprocessing.
//   blocks [0,768):    per-head transpose W{q,k,v} -> WT (hi/lo split)
//   blocks [768,1792):  Wo fp32 -> bf16
//   blocks [1792,5888): x fp32 -> hi/lo bf16 planes
// ---------------------------------------------------------------------------
__global__ __launch_bounds__(256) void prep_all(
    const float* __restrict__ x, const float* __restrict__ Wo,
    const float* __restrict__ Wq, const float* __restrict__ Wk, const float* __restrict__ Wv,
    unsigned short* __restrict__ xh, unsigned short* __restrict__ xl,
    unsigned short* __restrict__ WoB,
    unsigned short* __restrict__ WqTh, unsigned short* __restrict__ WqTl,
    unsigned short* __restrict__ WkTh, unsigned short* __restrict__ WkTl,
    unsigned short* __restrict__ WvT)
{
    __shared__ float tile[64][65];
    const int tid = threadIdx.x;
    const int bx = blockIdx.x;
    if (bx < 768) {
        const int et = bx & 15, h = (bx >> 4) & 15, m = bx >> 8;
        const float* W = (m == 0) ? Wq : (m == 1) ? Wk : Wv;
        #pragma unroll
        for (int rep = 0; rep < 4; ++rep) {
            int idx = rep * 256 + tid;            // f4 idx over [64e][16 i4]
            int e = idx >> 4, i4 = (idx & 15) * 4;
            facc v = *(const facc*)&W[(size_t)h * 65536 + (size_t)(et * 64 + e) * 64 + i4];
            tile[e][i4] = v.x; tile[e][i4 + 1] = v.y; tile[e][i4 + 2] = v.z; tile[e][i4 + 3] = v.w;
        }
        __syncthreads();
        unsigned short* Oh = (m == 0) ? WqTh : (m == 1) ? WkTh : WvT;
        unsigned short* Ol = (m == 0) ? WqTl : WkTl;
        #pragma unroll
        for (int rep = 0; rep < 4; ++rep) {
            int idx = rep * 256 + tid;            // [64 i][16 e4]
            int i = idx >> 4, e4 = (idx & 15) * 4;
            us4 hv, lv;
            #pragma unroll
            for (int j = 0; j < 4; ++j) {
                float f = tile[e4 + j][i];
                unsigned short hb = f2bh(f);
                hv[j] = hb;
                lv[j] = f2bh(f - bh2f(hb));
            }
            size_t o = (size_t)(h * 64 + i) * 1024 + et * 64 + e4;
            *(us4*)&Oh[o] = hv;
            if (m < 2) *(us4*)&Ol[o] = lv;
        }
    } else if (bx < 1792) {
        int idx = (bx - 768) * 256 + tid;         // f4 index, 262144 total
        facc v = *(const facc*)&Wo[(size_t)idx * 4];
        us4 o;
        #pragma unroll
        for (int j = 0; j < 4; ++j) o[j] = f2bh(v[j]);
        *(us4*)&WoB[(size_t)idx * 4] = o;
    } else {
        int idx = (bx - 1792) * 256 + tid;        // f4 idx, 1,048,576 total
        facc v = *(const facc*)&x[(size_t)idx * 4];
        us4 hv, lv;
        #pragma unroll
        for (int j = 0; j < 4; ++j) {
            unsigned short hb = f2bh(v[j]);
            hv[j] = hb;
            lv[j] = f2bh(v[j] - bh2f(hb));
        }
        *(us4*)&xh[(size_t)idx * 4] = hv;
        *(us4*)&xl[(size_t)idx * 4] = lv;
    }
}

// ---------------------------------------------------------------------------
// qkv_fused: block (ct, rt) computes q,k,v for rows [rt*128,+128), cols
// [ct*64,+64) in one K=1024 pass.  256 threads (4 waves, 2x2).  72KB dynamic
// LDS -> 2 blocks/CU (two independent barrier domains).  Counted-vmcnt
// pipeline (vmcnt(9)).  grid (16 ct, 32 rt) = 512 blocks = 2/CU exact.
// ---------------------------------------------------------------------------
__global__ __launch_bounds__(256, 2) void qkv_fused(
    const unsigned short* __restrict__ xh, const unsigned short* __restrict__ xl,
    const unsigned short* __restrict__ WqTh, const unsigned short* __restrict__ WqTl,
    const unsigned short* __restrict__ WkTh, const unsigned short* __restrict__ WkTl,
    const unsigned short* __restrict__ WvT,
    unsigned short* __restrict__ qh, unsigned char* __restrict__ ql8,
    unsigned short* __restrict__ kh, unsigned short* __restrict__ kl,
    unsigned short* __restrict__ vT)
{
    extern __shared__ unsigned short sm[];
    unsigned short* Ab = sm;               // [2][128*64] 32KB (x hi|lo, XOR-8 swz)
    unsigned short* Qb = sm + 16384;       // [2][64*64] 16KB
    unsigned short* Kb = sm + 24576;       // [2][64*64] 16KB
    unsigned short* Vb = sm + 32768;       // [2][64*32] 8KB  ((row>>1)&3 swz)
    const int tid = threadIdx.x;
    const int w = tid >> 6, l = tid & 63;
    const int wm = w >> 1, wn = w & 1;     // 2 x 2 wave grid
    const int ct = blockIdx.x, rt = blockIdx.y;

    const int lc = (l & 7) ^ (l >> 3);     // logical chunk at dest (128B rows)
    const int krel = (lc & 3) * 8;
    const unsigned short* Axp = (lc < 4) ? xh : xl;
    const unsigned short* Qp  = (lc < 4) ? WqTh : WqTl;
    const unsigned short* Kp  = (lc < 4) ? WkTh : WkTl;
    const int lcv = (l & 3) ^ ((l >> 3) & 3);   // V logical chunk (64B rows)

    facc accq[4][2], acck[4][2], accv[4][2];
    #pragma unroll
    for (int m = 0; m < 4; ++m)
        #pragma unroll
        for (int n = 0; n < 2; ++n) {
            accq[m][n] = (facc)(0.0f); acck[m][n] = (facc)(0.0f); accv[m][n] = (facc)(0.0f);
        }

    auto stageV = [&](int buf, int e0) {
        int row = w * 16 + (l >> 2);
        gl_lds16(&WvT[(size_t)(ct * 64 + row) * 1024 + e0 + lcv * 8],
                 &Vb[buf * 2048 + w * 512]);
    };

    // prologue: step 0
    {
        #pragma unroll
        for (int i = 0; i < 4; ++i) {
            int slice = w * 4 + i;
            int row = slice * 8 + (l >> 3);
            gl_lds16(&Axp[(size_t)(rt * 128 + row) * 1024 + krel], &Ab[slice * 512]);
        }
        #pragma unroll
        for (int i = 0; i < 2; ++i) {
            int slice = w * 2 + i;
            int row = slice * 8 + (l >> 3);
            size_t sb = (size_t)(ct * 64 + row) * 1024 + krel;
            gl_lds16(&Qp[sb], &Qb[slice * 512]);
            gl_lds16(&Kp[sb], &Kb[slice * 512]);
        }
        stageV(0, 0);
    }
    asm volatile("s_waitcnt vmcnt(0)" ::: "memory");
    __builtin_amdgcn_s_barrier();

    for (int t = 0; t < 32; ++t) {
        __builtin_amdgcn_s_barrier();              // bar1: all done with t-1 compute
        __builtin_amdgcn_sched_barrier(0);
        if (t < 31) {
            int buf = (t + 1) & 1, e0 = (t + 1) * 32;
            #pragma unroll
            for (int i = 0; i < 4; ++i) {
                int slice = w * 4 + i;
                int row = slice * 8 + (l >> 3);
                gl_lds16(&Axp[(size_t)(rt * 128 + row) * 1024 + e0 + krel],
                         &Ab[buf * 8192 + slice * 512]);
            }
            #pragma unroll
            for (int i = 0; i < 2; ++i) {
                int slice = w * 2 + i;
                int row = slice * 8 + (l >> 3);
                size_t sb = (size_t)(ct * 64 + row) * 1024 + e0 + krel;
                gl_lds16(&Qp[sb], &Qb[buf * 4096 + slice * 512]);
                gl_lds16(&Kp[sb], &Kb[buf * 4096 + slice * 512]);
            }
            stageV(buf, e0);
        }
        __builtin_amdgcn_sched_barrier(0);
        if (t < 31) asm volatile("s_waitcnt vmcnt(9)" ::: "memory");
        else        asm volatile("s_waitcnt vmcnt(0)" ::: "memory");
        __builtin_amdgcn_sched_barrier(0);
        __builtin_amdgcn_s_barrier();              // bar2: everyone's cur loads landed
        __builtin_amdgcn_sched_barrier(0);

        const unsigned short* Ac = &Ab[(t & 1) * 8192];
        const unsigned short* Qc = &Qb[(t & 1) * 4096];
        const unsigned short* Kc = &Kb[(t & 1) * 4096];
        const unsigned short* Vc = &Vb[(t & 1) * 2048];
        const int ca = (l >> 4) ^ (l & 7);         // phys chunk of hi frag (128B rows)
        const int cb = ca ^ 4;                     // lo frag

        bfrag afh[4], afl[4];
        #pragma unroll
        for (int m = 0; m < 4; ++m) {
            int row = wm * 64 + m * 16 + (l & 15);
            afh[m] = *(const bfrag*)&Ac[row * 64 + ca * 8];
            afl[m] = *(const bfrag*)&Ac[row * 64 + cb * 8];
        }
        #pragma unroll
        for (int n = 0; n < 2; ++n) {
            int nr = wn * 32 + n * 16 + (l & 15);
            int cv = (l >> 4) ^ ((nr >> 1) & 3);   // V phys chunk (64B rows)
            bfrag bv = *(const bfrag*)&Vc[nr * 32 + cv * 8];
            #pragma unroll
            for (int m = 0; m < 4; ++m) accv[m][n] = MFMA(afh[m], bv, accv[m][n]);
        }
        #pragma unroll
        for (int n = 0; n < 2; ++n) {
            int nr = wn * 32 + n * 16 + (l & 15);
            bfrag bh = *(const bfrag*)&Qc[nr * 64 + ca * 8];
            bfrag bl = *(const bfrag*)&Qc[nr * 64 + cb * 8];
            #pragma unroll
            for (int m = 0; m < 4; ++m) {
                accq[m][n] = MFMA(afh[m], bh, accq[m][n]);
                accq[m][n] = MFMA(afh[m], bl, accq[m][n]);
                accq[m][n] = MFMA(afl[m], bh, accq[m][n]);
            }
        }
        #pragma unroll
        for (int n = 0; n < 2; ++n) {
            int nr = wn * 32 + n * 16 + (l & 15);
            bfrag bh = *(const bfrag*)&Kc[nr * 64 + ca * 8];
            bfrag bl = *(const bfrag*)&Kc[nr * 64 + cb * 8];
            #pragma unroll
            for (int m = 0; m < 4; ++m) {
                acck[m][n] = MFMA(afh[m], bh, acck[m][n]);
                acck[m][n] = MFMA(afh[m], bl, acck[m][n]);
                acck[m][n] = MFMA(afl[m], bh, acck[m][n]);
            }
        }
    }

    // epilogue
    #pragma unroll
    for (int m = 0; m < 4; ++m)
        #pragma unroll
        for (int r = 0; r < 4; ++r) {
            int row = rt * 128 + wm * 64 + m * 16 + (l >> 4) * 4 + r;
            #pragma unroll
            for (int n = 0; n < 2; ++n) {
                int col = ct * 64 + wn * 32 + n * 16 + (l & 15);
                float fq = accq[m][n][r] * QSC;
                unsigned short hb = f2bh(fq);
                qh[(size_t)row * 1024 + col] = hb;
                __hip_fp8_e4m3 e((fq - bh2f(hb)) * 256.0f);
                ql8[(size_t)row * 1024 + col] = *reinterpret_cast<unsigned char*>(&e);
                float fk = acck[m][n][r];
                unsigned short kb = f2bh(fk);
                kh[(size_t)row * 1024 + col] = kb;
                kl[(size_t)row * 1024 + col] = f2bh(fk - bh2f(kb));
            }
        }
    // v: write transposed vT[(h*2+b)*64 + d][t], pack 4 consecutive t
    #pragma unroll
    for (int m = 0; m < 4; ++m) {
        int t0g = rt * 128 + wm * 64 + m * 16 + (l >> 4) * 4;
        int b_ = t0g >> 11, t0 = t0g & 2047;
        #pragma unroll
        for (int n = 0; n < 2; ++n) {
            int col = ct * 64 + wn * 32 + n * 16 + (l & 15);
            int h_ = col >> 6, d = col & 63;
            us4 pk;
            #pragma unroll
            for (int r = 0; r < 4; ++r) pk[r] = f2bh(accv[m][n][r]);
            *(us4*)&vT[((size_t)((h_ * 2 + b_) * 64 + d)) * 2048 + t0] = pk;
        }
    }
}

// ---------------------------------------------------------------------------
// attn helpers: per-wave 2-slice staging into a 64x64 tile.
// ---------------------------------------------------------------------------
__device__ __forceinline__ void stage_kh(
    const unsigned short* __restrict__ kh, unsigned short* Khb,
    int w, int l, int b, int h, int kt)
{
    #pragma unroll
    for (int i = 0; i < 2; ++i) {
        int pbase = (w * 2 + i) * 1024;
        int p = pbase + l * 16;
        int row = p >> 7, slot = (p >> 4) & 7;
        int chunk = slot ^ (row & 7);
        size_t src = (size_t)(b * 2048 + kt * 64 + row) * 1024 + h * 64 + chunk * 8;
        gl_lds16(&kh[src], &Khb[pbase >> 1]);
    }
}
__device__ __forceinline__ void stage_kl(
    const unsigned short* __restrict__ kl, unsigned short* Klb,
    int w, int l, int b, int h, int kt)
{
    #pragma unroll
    for (int i = 0; i < 2; ++i) {
        int pbase = (w * 2 + i) * 1024;
        int p = pbase + l * 16;
        int row = p >> 7, slot = (p >> 4) & 7;
        int chunk = slot ^ (row & 7);
        size_t src = (size_t)(b * 2048 + kt * 64 + row) * 1024 + h * 64 + chunk * 8;
        gl_lds16(&kl[src], &Klb[pbase >> 1]);
    }
}
__device__ __forceinline__ void stage_v(
    const unsigned short* __restrict__ vT, unsigned short* Vtb,
    int w, int l, int b, int h, int kt)
{
    #pragma unroll
    for (int i = 0; i < 2; ++i) {
        int pbase = (w * 2 + i) * 1024;
        int p = pbase + l * 16;
        int row = p >> 7, slot = (p >> 4) & 7;
        int chunk = slot ^ (row & 7);
        size_t srcV = ((size_t)(h * 2 + b) * 64 + row) * 2048 + (size_t)kt * 64 + chunk * 8;
        gl_lds16(&vT[srcV], &Vtb[pbase >> 1]);
    }
}

// ---------------------------------------------------------------------------
// attn_mfma: single-tile flash attention, 32KB LDS -> 4 blocks/CU GUARANTEED
// (128KB of 160KB; R12's 40KB x 4 = 160KB boundary did not fit -> occupancy
// stuck at 3).  ALL 1024 blocks resident; per-CU balanced (hb,qt) mapping
// (66 steps/CU).  Kh double-buffered (prefetch kt+1); Kl and V JIT single-
// buffered; P REUSES the Kl buffer after the lo-phase (B3 separates all
// waves' Kl reads from the P overwrite; each wave reads back only its own
// P rows, ordered by lgkmcnt).  vmcnt ladder: 6 -> 2 (prefetch never drained).
// ---------------------------------------------------------------------------
__global__ __launch_bounds__(256, 4) void attn_mfma(
    const unsigned short* __restrict__ qh, const unsigned char* __restrict__ ql8,
    const unsigned short* __restrict__ kh, const unsigned short* __restrict__ kl,
    const unsigned short* __restrict__ vT, unsigned short* __restrict__ att)
{
    __shared__ unsigned short Kh[2][4096], KlP[4096], Vt[4096];   // 32KB
    const int tid = threadIdx.x, w = tid >> 6, l = tid & 63;
    // residency-balanced mapping (round-robin dd->XCD): CU (xcd,c32) hosts
    // slots s=0..3 with hb = xcd*4 + s and qt = (s odd) ? c32 : 31-c32
    // -> per-CU steps = 66 uniform; 4 hb per XCD (K/V L2-resident).
    const int dd = blockIdx.y * 32 + blockIdx.x;
    const int s = dd >> 8, c = dd & 255;
    const int hb = (c & 7) * 4 + s;
    const int j = c >> 3;
    const int qt = (s & 1) ? j : 31 - j;
    const int h = hb >> 1, b = hb & 1;

    bfrag ones;
    #pragma unroll
    for (int jj = 0; jj < 8; ++jj) ones[jj] = (short)0x3F80;   // bf16 1.0

    bfrag qfh[2], qfl[2];
    {
        const int qrow = qt * 64 + w * 16 + (l & 15);
        const size_t qoff = (size_t)(b * 2048 + qrow) * 1024 + h * 64 + (l >> 4) * 8;
        qfh[0] = *(const bfrag*)&qh[qoff];
        qfh[1] = *(const bfrag*)&qh[qoff + 32];
        qfl[0] = f8frag(*(const uint2*)&ql8[qoff]);
        qfl[1] = f8frag(*(const uint2*)&ql8[qoff + 32]);
    }

    facc O[4], Osum;
    float mrow[4];
    #pragma unroll
    for (int f = 0; f < 4; ++f) O[f] = (facc)(0.0f);
    Osum = (facc)(0.0f);
    #pragma unroll
    for (int r = 0; r < 4; ++r) mrow[r] = -1e30f;

    stage_kh(kh, Kh[0], w, l, b, h, 0);          // prologue: 2 loads
    for (int kt = 0; kt <= qt; ++kt) {
        const int cur = kt & 1;
        __builtin_amdgcn_s_barrier();            // B0: WAR (prev step's reads done)
        __builtin_amdgcn_sched_barrier(0);
        stage_kl(kl, KlP, w, l, b, h, kt);       // JIT 2 loads
        stage_v(vT, Vt, w, l, b, h, kt);         // JIT 2 loads
        if (kt < qt)
            stage_kh(kh, Kh[cur ^ 1], w, l, b, h, kt + 1);   // prefetch 2 loads
        __builtin_amdgcn_sched_barrier(0);
        if (kt < qt) asm volatile("s_waitcnt vmcnt(6)" ::: "memory");  // Kh[cur] landed
        else         asm volatile("s_waitcnt vmcnt(4)" ::: "memory");
        __builtin_amdgcn_sched_barrier(0);
        __builtin_amdgcn_s_barrier();            // B1: Kh[cur] valid for all waves
        __builtin_amdgcn_sched_barrier(0);

        // ---- hi-phase QK^T: qh*kh + ql*kh (16 MFMA, prefetched Kh) ----
        facc S[4];
        #pragma unroll
        for (int f = 0; f < 4; ++f) S[f] = (facc)(0.0f);
        __builtin_amdgcn_s_setprio(1);
        #pragma unroll
        for (int sph = 0; sph < 2; ++sph) {
            #pragma unroll
            for (int f = 0; f < 4; ++f) {
                int key = f * 16 + (l & 15);
                int ch = (sph * 4 + (l >> 4)) ^ (key & 7);
                bfrag kbh = *(const bfrag*)&Kh[cur][key * 64 + ch * 8];
                S[f] = MFMA(qfh[sph], kbh, S[f]);
                S[f] = MFMA(qfl[sph], kbh, S[f]);
            }
        }
        __builtin_amdgcn_s_setprio(0);
        // ---- drain Kl/V (Kh prefetch stays in flight), sync ----
        __builtin_amdgcn_sched_barrier(0);
        if (kt < qt) asm volatile("s_waitcnt vmcnt(2)" ::: "memory");
        else         asm volatile("s_waitcnt vmcnt(0)" ::: "memory");
        __builtin_amdgcn_sched_barrier(0);
        __builtin_amdgcn_s_barrier();            // B2: KlP(=Kl), Vt valid
        __builtin_amdgcn_sched_barrier(0);
        // ---- lo-phase QK^T: qh*kl (8 MFMA) ----
        __builtin_amdgcn_s_setprio(1);
        #pragma unroll
        for (int sph = 0; sph < 2; ++sph) {
            #pragma unroll
            for (int f = 0; f < 4; ++f) {
                int key = f * 16 + (l & 15);
                int ch = (sph * 4 + (l >> 4)) ^ (key & 7);
                bfrag kbl = *(const bfrag*)&KlP[key * 64 + ch * 8];
                S[f] = MFMA(qfh[sph], kbl, S[f]);
            }
        }
        __builtin_amdgcn_s_setprio(0);
        if (kt == qt) {                          // causal mask on diagonal tile
            #pragma unroll
            for (int f = 0; f < 4; ++f) {
                int keyl = f * 16 + (l & 15);
                #pragma unroll
                for (int r = 0; r < 4; ++r) {
                    int qls = w * 16 + (l >> 4) * 4 + r;
                    if (keyl > qls) S[f][r] = -1e30f;
                }
            }
        }
        // ---- softmax: DPP row-max, defer-max (THR=8), exp2 ----
        float mx[4];
        float dmax = -3.0e38f;
        #pragma unroll
        for (int r = 0; r < 4; ++r) {
            float m0 = fmaxf(fmaxf(S[0][r], S[1][r]), fmaxf(S[2][r], S[3][r]));
            m0 = rowmax16(m0);
            mx[r] = m0;
            dmax = fmaxf(dmax, m0 - mrow[r]);
        }
        if (!__all(dmax <= 8.0f)) {              // wave-uniform, rare after warmup
            #pragma unroll
            for (int r = 0; r < 4; ++r) {
                float mn = fmaxf(mrow[r], mx[r]);
                float fac = EXP2(mrow[r] - mn);
                mrow[r] = mn;
                O[0][r] *= fac; O[1][r] *= fac; O[2][r] *= fac; O[3][r] *= fac;
                Osum[r] *= fac;
            }
        }
        #pragma unroll
        for (int r = 0; r < 4; ++r)
            #pragma unroll
            for (int f = 0; f < 4; ++f) S[f][r] = EXP2(S[f][r] - mrow[r]);
        // ---- B3: all waves finished reading Kl (their consuming MFMAs are
        // pre-B3, so the ds_reads have completed) -> safe to overwrite with P.
        __builtin_amdgcn_sched_barrier(0);
        __builtin_amdgcn_s_barrier();
        __builtin_amdgcn_sched_barrier(0);
        // P -> KlP (bf16, swizzled rows; each wave writes ONLY its own rows)
        #pragma unroll
        for (int f = 0; f < 4; ++f) {
            int key = f * 16 + (l & 15);
            #pragma unroll
            for (int r = 0; r < 4; ++r) {
                int qr = w * 16 + (l >> 4) * 4 + r;
                KlP[qr * 64 + (((key >> 3) ^ (qr & 7)) * 8) + (key & 7)] = f2bh(S[f][r]);
            }
        }
        // ---- PV + denominator via ones-MFMA (P read back from own rows) ----
        __builtin_amdgcn_s_setprio(1);
        #pragma unroll
        for (int sph = 0; sph < 2; ++sph) {
            int qa = w * 16 + (l & 15);
            int cha = (sph * 4 + (l >> 4)) ^ (qa & 7);
            bfrag pa = *(const bfrag*)&KlP[qa * 64 + cha * 8];
            Osum = MFMA(pa, ones, Osum);
            #pragma unroll
            for (int f = 0; f < 4; ++f) {
                int d = f * 16 + (l & 15);
                int chv = (sph * 4 + (l >> 4)) ^ (d & 7);
                bfrag vb = *(const bfrag*)&Vt[d * 64 + chv * 8];
                O[f] = MFMA(pa, vb, O[f]);
            }
        }
        __builtin_amdgcn_s_setprio(0);
    }

    #pragma unroll
    for (int f = 0; f < 4; ++f) {
        int d = h * 64 + f * 16 + (l & 15);
        #pragma unroll
        for (int r = 0; r < 4; ++r) {
            int t = qt * 64 + w * 16 + (l >> 4) * 4 + r;
            att[(size_t)(b * 2048 + t) * 1024 + d] = f2bh(O[f][r] / Osum[r]);
        }
    }
}

// ---------------------------------------------------------------------------
// outproj: out[4096,1024] = att @ Wo^T.  BK=64 swizzled, double-buffered with
// the prefetch-across-raw-barrier loop.  grid (32, 8), 64KB LDS.
// ---------------------------------------------------------------------------
__global__ __launch_bounds__(256, 2) void outproj(
    const unsigned short* __restrict__ att, const unsigned short* __restrict__ WoB,
    float* __restrict__ out)
{
    __shared__ unsigned short Ab[2][128 * 64], Bb[2][128 * 64];
    const int tid = threadIdx.x, w = tid >> 6, l = tid & 63;
    const int wm = w >> 1, wn = w & 1;
    const int rt = blockIdx.x, ct = blockIdx.y;

    const int lc = (l & 7) ^ (l >> 3);         // logical chunk (0..7) -> k-offset lc*8
    facc acc[4][4];
    #pragma unroll
    for (int i = 0; i < 4; ++i)
        #pragma unroll
        for (int j = 0; j < 4; ++j) acc[i][j] = (facc)(0.0f);

    auto stage = [&](int buf, int e0) {
        #pragma unroll
        for (int i = 0; i < 4; ++i) {
            int slice = w * 4 + i;
            int row = slice * 8 + (l >> 3);
            gl_lds16(&att[(size_t)(rt * 128 + row) * 1024 + e0 + lc * 8], &Ab[buf][slice * 512]);
            gl_lds16(&WoB[(size_t)(ct * 128 + row) * 1024 + e0 + lc * 8], &Bb[buf][slice * 512]);
        }
    };

    stage(0, 0);
    int cur = 0;
    for (int t = 0; t < 16; ++t) {
        __syncthreads();
        if (t < 15) stage(cur ^ 1, (t + 1) * 64);
        __builtin_amdgcn_sched_barrier(0);
        __builtin_amdgcn_s_barrier();
        __builtin_amdgcn_sched_barrier(0);
        #pragma unroll
        for (int s = 0; s < 2; ++s) {
            const int slot = (s * 4 + (l >> 4)) ^ (l & 7);
            bfrag af[4], bf_[4];
            #pragma unroll
            for (int m = 0; m < 4; ++m)
                af[m] = *(const bfrag*)&Ab[cur][(wm * 64 + m * 16 + (l & 15)) * 64 + slot * 8];
            #pragma unroll
            for (int n = 0; n < 4; ++n)
                bf_[n] = *(const bfrag*)&Bb[cur][(wn * 64 + n * 16 + (l & 15)) * 64 + slot * 8];
            #pragma unroll
            for (int m = 0; m < 4; ++m)
                #pragma unroll
                for (int n = 0; n < 4; ++n)
                    acc[m][n] = MFMA(af[m], bf_[n], acc[m][n]);
        }
        cur ^= 1;
    }
    #pragma unroll
    for (int m = 0; m < 4; ++m)
        #pragma unroll
        for (int r = 0; r < 4; ++r) {
            int row = rt * 128 + wm * 64 + m * 16 + (l >> 4) * 4 + r;
            #pragma unroll
            for (int n = 0; n < 4; ++n) {
                int col = ct * 128 + wn * 64 + n * 16 + (l & 15);
                out[(size_t)row * 1024 + col] = acc[m][n][r];
            }
        }
}

// ---------------------------------------------------------------------------
extern "C" void kernel_launch(void* const* d_in, const int* in_sizes, int n_in,
                              void* d_out, int out_size, void* d_ws, size_t ws_size,
                              hipStream_t stream) {
    const float* x  = (const float*)d_in[0];
    // d_in[1]: causal mask (applied analytically)
    const float* Wq = (const float*)d_in[2];
    const float* Wk = (const float*)d_in[3];
    const float* Wv = (const float*)d_in[4];
    const float* Wo = (const float*)d_in[5];

    uint8_t* wsb = (uint8_t*)d_ws;
    const size_t MB = 1024 * 1024;
    // 64MB layout.  xh overlays att (xh dead before attn writes att).
    unsigned short* WqTh = (unsigned short*)(wsb + 0 * MB);
    unsigned short* WqTl = (unsigned short*)(wsb + 2 * MB);
    unsigned short* WkTh = (unsigned short*)(wsb + 4 * MB);
    unsigned short* WkTl = (unsigned short*)(wsb + 6 * MB);
    unsigned short* WvT  = (unsigned short*)(wsb + 8 * MB);
    unsigned short* qh   = (unsigned short*)(wsb + 10 * MB);  // 8MB
    unsigned char*  ql8  = (unsigned char*)(wsb + 18 * MB);   // 4MB fp8
    unsigned short* kh   = (unsigned short*)(wsb + 22 * MB);  // 8MB
    unsigned short* kl   = (unsigned short*)(wsb + 30 * MB);  // 8MB
    unsigned short* vT   = (unsigned short*)(wsb + 38 * MB);  // 8MB
    unsigned short* att  = (unsigned short*)(wsb + 46 * MB);  // 8MB
    unsigned short* xh   = (unsigned short*)(wsb + 46 * MB);  // 8MB (alias att)
    unsigned short* WoB  = (unsigned short*)(wsb + 54 * MB);  // 2MB
    unsigned short* xl   = (unsigned short*)(wsb + 56 * MB);  // 8MB

    hipFuncSetAttribute((const void*)qkv_fused,
                        hipFuncAttributeMaxDynamicSharedMemorySize, 73728);

    prep_all<<<dim3(5888), 256, 0, stream>>>(x, Wo, Wq, Wk, Wv, xh, xl, WoB,
                                             WqTh, WqTl, WkTh, WkTl, WvT);
    qkv_fused<<<dim3(16, 32), 256, 73728, stream>>>(xh, xl, WqTh, WqTl, WkTh, WkTl, WvT,
                                                    qh, ql8, kh, kl, vT);
    attn_mfma<<<dim3(32, 32), 256, 0, stream>>>(qh, ql8, kh, kl, vT, att);
    outproj<<<dim3(32, 8), 256, 0, stream>>>(att, WoB, (float*)d_out);
}

// Round 15
// 152.880 us; speedup vs baseline: 1.0889x; 1.0889x over previous
//
#include <hip/hip_runtime.h>
#include <hip/hip_fp8.h>
#include <stdint.h>

// (B,T,E,H,D) = (2,2048,1024,16,64)
constexpr float INV_SCALE = 0.022097086912079608f;  // 1/sqrt(2048)
constexpr float LOG2E = 1.4426950408889634f;
constexpr float QSC = INV_SCALE * LOG2E;            // q pre-scale: softmax in exp2 domain

typedef __attribute__((ext_vector_type(8))) short bfrag;          // 8 bf16 (4 VGPR) MFMA frag
typedef __attribute__((ext_vector_type(4))) float facc;           // 4 f32 MFMA acc
typedef __attribute__((ext_vector_type(4))) unsigned short us4;   // 4 bf16 = 8B

#define MFMA(a, b, c) __builtin_amdgcn_mfma_f32_16x16x32_bf16((a), (b), (c), 0, 0, 0)
#define EXP2(x) __builtin_amdgcn_exp2f(x)

__device__ __forceinline__ unsigned short f2bh(float f) {        // f32 -> bf16 RNE
    union { float f; unsigned int u; } cv; cv.f = f;
    unsigned int u = cv.u;
    u += 0x7FFFu + ((u >> 16) & 1u);
    return (unsigned short)(u >> 16);
}
__device__ __forceinline__ float bh2f(unsigned short h) {
    union { unsigned int u; float f; } cv; cv.u = ((unsigned int)h) << 16;
    return cv.f;
}
__device__ __forceinline__ void gl_lds16(const unsigned short* g, unsigned short* lds) {
    // async 16B/lane global->LDS; dst is wave-uniform base, lane i lands at dst+16*i
    __builtin_amdgcn_global_load_lds(
        (const __attribute__((address_space(1))) unsigned int*)g,
        (__attribute__((address_space(3))) unsigned int*)lds, 16, 0, 0);
}
// 8 fp8(e4m3, x256) bytes -> bf16 frag (undo the 256x scale)
__device__ __forceinline__ bfrag f8frag(uint2 raw) {
    union { uint2 u; unsigned char b[8]; } cv; cv.u = raw;
    bfrag r;
    #pragma unroll
    for (int j = 0; j < 8; ++j) {
        const __hip_fp8_e4m3* t = reinterpret_cast<const __hip_fp8_e4m3*>(&cv.b[j]);
        r[j] = (short)f2bh((float)(*t) * 0.00390625f);
    }
    return r;
}
// one DPP max-reduce stage over the 16-lane row (pure VALU, no LDS)
template<int CTRL>
__device__ __forceinline__ float dppmax(float v) {
    int s = __builtin_amdgcn_update_dpp(0, __builtin_bit_cast(int, v), CTRL, 0xF, 0xF, true);
    return fmaxf(v, __builtin_bit_cast(float, s));
}
__device__ __forceinline__ float rowmax16(float v) {
    v = dppmax<0xB1>(v);    // quad_perm [1,0,3,2]  (xor 1)
    v = dppmax<0x4E>(v);    // quad_perm [2,3,0,1]  (xor 2)
    v = dppmax<0x141>(v);   // row_half_mirror      (covers xor 4)
    v = dppmax<0x140>(v);   // row_mirror           (covers xor 8)
    return v;
}

// ---------------------------------------------------------------------------
// prep_all: ONE launch for all preprocessing.
//   blocks [0,768):    per-head transpose W{q,k,v} -> WT (hi/lo split)
//   blocks [768,1792):  Wo fp32 -> bf16
//   blocks [1792,5888): x fp32 -> hi/lo bf16 planes
// ---------------------------------------------------------------------------
__global__ __launch_bounds__(256) void prep_all(
    const float* __restrict__ x, const float* __restrict__ Wo,
    const float* __restrict__ Wq, const float* __restrict__ Wk, const float* __restrict__ Wv,
    unsigned short* __restrict__ xh, unsigned short* __restrict__ xl,
    unsigned short* __restrict__ WoB,
    unsigned short* __restrict__ WqTh, unsigned short* __restrict__ WqTl,
    unsigned short* __restrict__ WkTh, unsigned short* __restrict__ WkTl,
    unsigned short* __restrict__ WvT)
{
    __shared__ float tile[64][65];
    const int tid = threadIdx.x;
    const int bx = blockIdx.x;
    if (bx < 768) {
        const int et = bx & 15, h = (bx >> 4) & 15, m = bx >> 8;
        const float* W = (m == 0) ? Wq : (m == 1) ? Wk : Wv;
        #pragma unroll
        for (int rep = 0; rep < 4; ++rep) {
            int idx = rep * 256 + tid;            // f4 idx over [64e][16 i4]
            int e = idx >> 4, i4 = (idx & 15) * 4;
            facc v = *(const facc*)&W[(size_t)h * 65536 + (size_t)(et * 64 + e) * 64 + i4];
            tile[e][i4] = v.x; tile[e][i4 + 1] = v.y; tile[e][i4 + 2] = v.z; tile[e][i4 + 3] = v.w;
        }
        __syncthreads();
        unsigned short* Oh = (m == 0) ? WqTh : (m == 1) ? WkTh : WvT;
        unsigned short* Ol = (m == 0) ? WqTl : WkTl;
        #pragma unroll
        for (int rep = 0; rep < 4; ++rep) {
            int idx = rep * 256 + tid;            // [64 i][16 e4]
            int i = idx >> 4, e4 = (idx & 15) * 4;
            us4 hv, lv;
            #pragma unroll
            for (int j = 0; j < 4; ++j) {
                float f = tile[e4 + j][i];
                unsigned short hb = f2bh(f);
                hv[j] = hb;
                lv[j] = f2bh(f - bh2f(hb));
            }
            size_t o = (size_t)(h * 64 + i) * 1024 + et * 64 + e4;
            *(us4*)&Oh[o] = hv;
            if (m < 2) *(us4*)&Ol[o] = lv;
        }
    } else if (bx < 1792) {
        int idx = (bx - 768) * 256 + tid;         // f4 index, 262144 total
        facc v = *(const facc*)&Wo[(size_t)idx * 4];
        us4 o;
        #pragma unroll
        for (int j = 0; j < 4; ++j) o[j] = f2bh(v[j]);
        *(us4*)&WoB[(size_t)idx * 4] = o;
    } else {
        int idx = (bx - 1792) * 256 + tid;        // f4 idx, 1,048,576 total
        facc v = *(const facc*)&x[(size_t)idx * 4];
        us4 hv, lv;
        #pragma unroll
        for (int j = 0; j < 4; ++j) {
            unsigned short hb = f2bh(v[j]);
            hv[j] = hb;
            lv[j] = f2bh(v[j] - bh2f(hb));
        }
        *(us4*)&xh[(size_t)idx * 4] = hv;
        *(us4*)&xl[(size_t)idx * 4] = lv;
    }
}

// ---------------------------------------------------------------------------
// qkv_fused: block (ct, rt) computes q,k,v for rows [rt*128,+128), cols
// [ct*64,+64) in one K=1024 pass.  256 threads (4 waves, 2x2).  72KB dynamic
// LDS -> 2 blocks/CU (two independent barrier domains).  Counted-vmcnt
// pipeline (vmcnt(9)).  grid (16 ct, 32 rt) = 512 blocks = 2/CU exact.
// ---------------------------------------------------------------------------
__global__ __launch_bounds__(256, 2) void qkv_fused(
    const unsigned short* __restrict__ xh, const unsigned short* __restrict__ xl,
    const unsigned short* __restrict__ WqTh, const unsigned short* __restrict__ WqTl,
    const unsigned short* __restrict__ WkTh, const unsigned short* __restrict__ WkTl,
    const unsigned short* __restrict__ WvT,
    unsigned short* __restrict__ qh, unsigned char* __restrict__ ql8,
    unsigned short* __restrict__ kh, unsigned short* __restrict__ kl,
    unsigned short* __restrict__ vT)
{
    extern __shared__ unsigned short sm[];
    unsigned short* Ab = sm;               // [2][128*64] 32KB (x hi|lo, XOR-8 swz)
    unsigned short* Qb = sm + 16384;       // [2][64*64] 16KB
    unsigned short* Kb = sm + 24576;       // [2][64*64] 16KB
    unsigned short* Vb = sm + 32768;       // [2][64*32] 8KB  ((row>>1)&3 swz)
    const int tid = threadIdx.x;
    const int w = tid >> 6, l = tid & 63;
    const int wm = w >> 1, wn = w & 1;     // 2 x 2 wave grid
    const int ct = blockIdx.x, rt = blockIdx.y;

    const int lc = (l & 7) ^ (l >> 3);     // logical chunk at dest (128B rows)
    const int krel = (lc & 3) * 8;
    const unsigned short* Axp = (lc < 4) ? xh : xl;
    const unsigned short* Qp  = (lc < 4) ? WqTh : WqTl;
    const unsigned short* Kp  = (lc < 4) ? WkTh : WkTl;
    const int lcv = (l & 3) ^ ((l >> 3) & 3);   // V logical chunk (64B rows)

    facc accq[4][2], acck[4][2], accv[4][2];
    #pragma unroll
    for (int m = 0; m < 4; ++m)
        #pragma unroll
        for (int n = 0; n < 2; ++n) {
            accq[m][n] = (facc)(0.0f); acck[m][n] = (facc)(0.0f); accv[m][n] = (facc)(0.0f);
        }

    auto stageV = [&](int buf, int e0) {
        int row = w * 16 + (l >> 2);
        gl_lds16(&WvT[(size_t)(ct * 64 + row) * 1024 + e0 + lcv * 8],
                 &Vb[buf * 2048 + w * 512]);
    };

    // prologue: step 0
    {
        #pragma unroll
        for (int i = 0; i < 4; ++i) {
            int slice = w * 4 + i;
            int row = slice * 8 + (l >> 3);
            gl_lds16(&Axp[(size_t)(rt * 128 + row) * 1024 + krel], &Ab[slice * 512]);
        }
        #pragma unroll
        for (int i = 0; i < 2; ++i) {
            int slice = w * 2 + i;
            int row = slice * 8 + (l >> 3);
            size_t sb = (size_t)(ct * 64 + row) * 1024 + krel;
            gl_lds16(&Qp[sb], &Qb[slice * 512]);
            gl_lds16(&Kp[sb], &Kb[slice * 512]);
        }
        stageV(0, 0);
    }
    asm volatile("s_waitcnt vmcnt(0)" ::: "memory");
    __builtin_amdgcn_s_barrier();

    for (int t = 0; t < 32; ++t) {
        __builtin_amdgcn_s_barrier();              // bar1: all done with t-1 compute
        __builtin_amdgcn_sched_barrier(0);
        if (t < 31) {
            int buf = (t + 1) & 1, e0 = (t + 1) * 32;
            #pragma unroll
            for (int i = 0; i < 4; ++i) {
                int slice = w * 4 + i;
                int row = slice * 8 + (l >> 3);
                gl_lds16(&Axp[(size_t)(rt * 128 + row) * 1024 + e0 + krel],
                         &Ab[buf * 8192 + slice * 512]);
            }
            #pragma unroll
            for (int i = 0; i < 2; ++i) {
                int slice = w * 2 + i;
                int row = slice * 8 + (l >> 3);
                size_t sb = (size_t)(ct * 64 + row) * 1024 + e0 + krel;
                gl_lds16(&Qp[sb], &Qb[buf * 4096 + slice * 512]);
                gl_lds16(&Kp[sb], &Kb[buf * 4096 + slice * 512]);
            }
            stageV(buf, e0);
        }
        __builtin_amdgcn_sched_barrier(0);
        if (t < 31) asm volatile("s_waitcnt vmcnt(9)" ::: "memory");
        else        asm volatile("s_waitcnt vmcnt(0)" ::: "memory");
        __builtin_amdgcn_sched_barrier(0);
        __builtin_amdgcn_s_barrier();              // bar2: everyone's cur loads landed
        __builtin_amdgcn_sched_barrier(0);

        const unsigned short* Ac = &Ab[(t & 1) * 8192];
        const unsigned short* Qc = &Qb[(t & 1) * 4096];
        const unsigned short* Kc = &Kb[(t & 1) * 4096];
        const unsigned short* Vc = &Vb[(t & 1) * 2048];
        const int ca = (l >> 4) ^ (l & 7);         // phys chunk of hi frag (128B rows)
        const int cb = ca ^ 4;                     // lo frag

        bfrag afh[4], afl[4];
        #pragma unroll
        for (int m = 0; m < 4; ++m) {
            int row = wm * 64 + m * 16 + (l & 15);
            afh[m] = *(const bfrag*)&Ac[row * 64 + ca * 8];
            afl[m] = *(const bfrag*)&Ac[row * 64 + cb * 8];
        }
        #pragma unroll
        for (int n = 0; n < 2; ++n) {
            int nr = wn * 32 + n * 16 + (l & 15);
            int cv = (l >> 4) ^ ((nr >> 1) & 3);   // V phys chunk (64B rows)
            bfrag bv = *(const bfrag*)&Vc[nr * 32 + cv * 8];
            #pragma unroll
            for (int m = 0; m < 4; ++m) accv[m][n] = MFMA(afh[m], bv, accv[m][n]);
        }
        #pragma unroll
        for (int n = 0; n < 2; ++n) {
            int nr = wn * 32 + n * 16 + (l & 15);
            bfrag bh = *(const bfrag*)&Qc[nr * 64 + ca * 8];
            bfrag bl = *(const bfrag*)&Qc[nr * 64 + cb * 8];
            #pragma unroll
            for (int m = 0; m < 4; ++m) {
                accq[m][n] = MFMA(afh[m], bh, accq[m][n]);
                accq[m][n] = MFMA(afh[m], bl, accq[m][n]);
                accq[m][n] = MFMA(afl[m], bh, accq[m][n]);
            }
        }
        #pragma unroll
        for (int n = 0; n < 2; ++n) {
            int nr = wn * 32 + n * 16 + (l & 15);
            bfrag bh = *(const bfrag*)&Kc[nr * 64 + ca * 8];
            bfrag bl = *(const bfrag*)&Kc[nr * 64 + cb * 8];
            #pragma unroll
            for (int m = 0; m < 4; ++m) {
                acck[m][n] = MFMA(afh[m], bh, acck[m][n]);
                acck[m][n] = MFMA(afh[m], bl, acck[m][n]);
                acck[m][n] = MFMA(afl[m], bh, acck[m][n]);
            }
        }
    }

    // epilogue
    #pragma unroll
    for (int m = 0; m < 4; ++m)
        #pragma unroll
        for (int r = 0; r < 4; ++r) {
            int row = rt * 128 + wm * 64 + m * 16 + (l >> 4) * 4 + r;
            #pragma unroll
            for (int n = 0; n < 2; ++n) {
                int col = ct * 64 + wn * 32 + n * 16 + (l & 15);
                float fq = accq[m][n][r] * QSC;
                unsigned short hb = f2bh(fq);
                qh[(size_t)row * 1024 + col] = hb;
                __hip_fp8_e4m3 e((fq - bh2f(hb)) * 256.0f);
                ql8[(size_t)row * 1024 + col] = *reinterpret_cast<unsigned char*>(&e);
                float fk = acck[m][n][r];
                unsigned short kb = f2bh(fk);
                kh[(size_t)row * 1024 + col] = kb;
                kl[(size_t)row * 1024 + col] = f2bh(fk - bh2f(kb));
            }
        }
    // v: write transposed vT[(h*2+b)*64 + d][t], pack 4 consecutive t
    #pragma unroll
    for (int m = 0; m < 4; ++m) {
        int t0g = rt * 128 + wm * 64 + m * 16 + (l >> 4) * 4;
        int b_ = t0g >> 11, t0 = t0g & 2047;
        #pragma unroll
        for (int n = 0; n < 2; ++n) {
            int col = ct * 64 + wn * 32 + n * 16 + (l & 15);
            int h_ = col >> 6, d = col & 63;
            us4 pk;
            #pragma unroll
            for (int r = 0; r < 4; ++r) pk[r] = f2bh(accv[m][n][r]);
            *(us4*)&vT[((size_t)((h_ * 2 + b_) * 64 + d)) * 2048 + t0] = pk;
        }
    }
}

// ---------------------------------------------------------------------------
// attn helpers
// ---------------------------------------------------------------------------
__device__ __forceinline__ void stage_k(
    const unsigned short* __restrict__ kh, const unsigned short* __restrict__ kl,
    unsigned short* Khb, unsigned short* Klb, int w, int l, int b, int h, int kt)
{
    #pragma unroll
    for (int i = 0; i < 2; ++i) {
        int pbase = (w * 2 + i) * 1024;    // uniform 1KB slice base (bytes)
        int p = pbase + l * 16;
        int row = p >> 7, slot = (p >> 4) & 7;
        int chunk = slot ^ (row & 7);      // inverse-swizzled source chunk
        size_t srcK = (size_t)(b * 2048 + kt * 64 + row) * 1024 + h * 64 + chunk * 8;
        gl_lds16(&kh[srcK], &Khb[pbase >> 1]);
        gl_lds16(&kl[srcK], &Klb[pbase >> 1]);
    }
}
__device__ __forceinline__ void stage_v(
    const unsigned short* __restrict__ vT, unsigned short* Vtb,
    int w, int l, int b, int h, int kt)
{
    #pragma unroll
    for (int i = 0; i < 2; ++i) {
        int pbase = (w * 2 + i) * 1024;
        int p = pbase + l * 16;
        int row = p >> 7, slot = (p >> 4) & 7;
        int chunk = slot ^ (row & 7);
        size_t srcV = ((size_t)(h * 2 + b) * 64 + row) * 2048 + (size_t)kt * 64 + chunk * 8;
        gl_lds16(&vT[srcV], &Vtb[pbase >> 1]);
    }
}

// ---------------------------------------------------------------------------
// attn_mfma: de-paired single-tile flash attention (R11 structure -- best
// measured).  grid (32, 32) = 1024 blocks (one 64-row q-tile each), 4 waves,
// 48KB static LDS -> 3 blocks/CU.  qt-major DESCENDING dispatch order
// (longest blocks first) lets the HW scheduler backfill the causal imbalance.
// K hi/lo double-buffered (prefetch across raw barrier); V single-buffered
// just-in-time: staged at iter top, drained by counted vmcnt(4) + raw
// barrier before PV.
// ---------------------------------------------------------------------------
__global__ __launch_bounds__(256, 3) void attn_mfma(
    const unsigned short* __restrict__ qh, const unsigned char* __restrict__ ql8,
    const unsigned short* __restrict__ kh, const unsigned short* __restrict__ kl,
    const unsigned short* __restrict__ vT, unsigned short* __restrict__ att)
{
    __shared__ unsigned short Kh[2][4096], Kl[2][4096], Vt[4096], Pl[4096];
    const int tid = threadIdx.x, w = tid >> 6, l = tid & 63;
    // dd ascending = dispatch order.  qt-major descending; XCD-striped hb.
    const int dd = blockIdx.y * 32 + blockIdx.x;
    const int xcd = dd & 7, sl = dd >> 3;          // sl in 0..127
    const int qt = 31 - (sl >> 2);                 // first dispatched = qt 31
    const int hb = xcd * 4 + (sl & 3);             // 4 hb per XCD (K/V L2-resident)
    const int h = hb >> 1, b = hb & 1;

    bfrag ones;
    #pragma unroll
    for (int j = 0; j < 8; ++j) ones[j] = (short)0x3F80;   // bf16 1.0

    bfrag qfh[2], qfl[2];
    {
        const int qrow = qt * 64 + w * 16 + (l & 15);
        const size_t qoff = (size_t)(b * 2048 + qrow) * 1024 + h * 64 + (l >> 4) * 8;
        qfh[0] = *(const bfrag*)&qh[qoff];
        qfh[1] = *(const bfrag*)&qh[qoff + 32];
        qfl[0] = f8frag(*(const uint2*)&ql8[qoff]);
        qfl[1] = f8frag(*(const uint2*)&ql8[qoff + 32]);
    }

    facc O[4], Osum;
    float mrow[4];
    #pragma unroll
    for (int f = 0; f < 4; ++f) O[f] = (facc)(0.0f);
    Osum = (facc)(0.0f);
    #pragma unroll
    for (int r = 0; r < 4; ++r) mrow[r] = -1e30f;

    stage_k(kh, kl, Kh[0], Kl[0], w, l, b, h, 0);
    for (int kt = 0; kt <= qt; ++kt) {
        const int cur = kt & 1;
        __syncthreads();                   // drains prior loads; WAR on K^1 and Vt
        stage_v(vT, Vt, w, l, b, h, kt);   // just-in-time V (2 loads)
        if (kt < qt)
            stage_k(kh, kl, Kh[cur ^ 1], Kl[cur ^ 1], w, l, b, h, kt + 1);  // 4 loads
        __builtin_amdgcn_sched_barrier(0);
        __builtin_amdgcn_s_barrier();      // all waves past their drain -> K[cur] valid
        __builtin_amdgcn_sched_barrier(0);

        // ---- QK^T (split 3-term) ----
        facc S[4];
        #pragma unroll
        for (int f = 0; f < 4; ++f) S[f] = (facc)(0.0f);
        __builtin_amdgcn_s_setprio(1);
        #pragma unroll
        for (int s = 0; s < 2; ++s) {
            #pragma unroll
            for (int f = 0; f < 4; ++f) {
                int key = f * 16 + (l & 15);
                int ch = (s * 4 + (l >> 4)) ^ (key & 7);
                bfrag kbh = *(const bfrag*)&Kh[cur][key * 64 + ch * 8];
                bfrag kbl = *(const bfrag*)&Kl[cur][key * 64 + ch * 8];
                S[f] = MFMA(qfh[s], kbh, S[f]);
                S[f] = MFMA(qfh[s], kbl, S[f]);
                S[f] = MFMA(qfl[s], kbh, S[f]);
            }
        }
        __builtin_amdgcn_s_setprio(0);
        if (kt == qt) {                    // causal mask on diagonal tile
            #pragma unroll
            for (int f = 0; f < 4; ++f) {
                int keyl = f * 16 + (l & 15);
                #pragma unroll
                for (int r = 0; r < 4; ++r) {
                    int qls = w * 16 + (l >> 4) * 4 + r;
                    if (keyl > qls) S[f][r] = -1e30f;
                }
            }
        }
        // ---- softmax: DPP row-max, defer-max (THR=8), exp2 ----
        float mx[4];
        float dmax = -3.0e38f;
        #pragma unroll
        for (int r = 0; r < 4; ++r) {
            float m0 = fmaxf(fmaxf(S[0][r], S[1][r]), fmaxf(S[2][r], S[3][r]));
            m0 = rowmax16(m0);
            mx[r] = m0;
            dmax = fmaxf(dmax, m0 - mrow[r]);
        }
        if (!__all(dmax <= 8.0f)) {        // wave-uniform, rare after warmup
            #pragma unroll
            for (int r = 0; r < 4; ++r) {
                float mn = fmaxf(mrow[r], mx[r]);
                float fac = EXP2(mrow[r] - mn);
                mrow[r] = mn;
                O[0][r] *= fac; O[1][r] *= fac; O[2][r] *= fac; O[3][r] *= fac;
                Osum[r] *= fac;
            }
        }
        #pragma unroll
        for (int r = 0; r < 4; ++r)
            #pragma unroll
            for (int f = 0; f < 4; ++f) S[f][r] = EXP2(S[f][r] - mrow[r]);
        // P -> LDS (bf16, swizzled rows; same-wave rows only)
        #pragma unroll
        for (int f = 0; f < 4; ++f) {
            int key = f * 16 + (l & 15);
            #pragma unroll
            for (int r = 0; r < 4; ++r) {
                int qr = w * 16 + (l >> 4) * 4 + r;
                Pl[qr * 64 + (((key >> 3) ^ (qr & 7)) * 8) + (key & 7)] = f2bh(S[f][r]);
            }
        }
        // ---- drain my V loads (K prefetch stays in flight), then sync ----
        __builtin_amdgcn_sched_barrier(0);
        if (kt < qt) asm volatile("s_waitcnt vmcnt(4)" ::: "memory");
        else         asm volatile("s_waitcnt vmcnt(0)" ::: "memory");
        __builtin_amdgcn_sched_barrier(0);
        __builtin_amdgcn_s_barrier();      // every wave's V landed -> Vt valid
        __builtin_amdgcn_sched_barrier(0);
        // ---- PV + denominator via ones-MFMA ----
        __builtin_amdgcn_s_setprio(1);
        #pragma unroll
        for (int s = 0; s < 2; ++s) {
            int qa = w * 16 + (l & 15);
            int cha = (s * 4 + (l >> 4)) ^ (qa & 7);
            bfrag pa = *(const bfrag*)&Pl[qa * 64 + cha * 8];
            Osum = MFMA(pa, ones, Osum);
            #pragma unroll
            for (int f = 0; f < 4; ++f) {
                int d = f * 16 + (l & 15);
                int chv = (s * 4 + (l >> 4)) ^ (d & 7);
                bfrag vb = *(const bfrag*)&Vt[d * 64 + chv * 8];
                O[f] = MFMA(pa, vb, O[f]);
            }
        }
        __builtin_amdgcn_s_setprio(0);
    }

    #pragma unroll
    for (int f = 0; f < 4; ++f) {
        int d = h * 64 + f * 16 + (l & 15);
        #pragma unroll
        for (int r = 0; r < 4; ++r) {
            int t = qt * 64 + w * 16 + (l >> 4) * 4 + r;
            att[(size_t)(b * 2048 + t) * 1024 + d] = f2bh(O[f][r] / Osum[r]);
        }
    }
}

// ---------------------------------------------------------------------------
// outproj: out[4096,1024] = att @ Wo^T.  BK=64 swizzled, double-buffered with
// the prefetch-across-raw-barrier loop.  grid (32, 8), 64KB LDS.
// ---------------------------------------------------------------------------
__global__ __launch_bounds__(256, 2) void outproj(
    const unsigned short* __restrict__ att, const unsigned short* __restrict__ WoB,
    float* __restrict__ out)
{
    __shared__ unsigned short Ab[2][128 * 64], Bb[2][128 * 64];
    const int tid = threadIdx.x, w = tid >> 6, l = tid & 63;
    const int wm = w >> 1, wn = w & 1;
    const int rt = blockIdx.x, ct = blockIdx.y;

    const int lc = (l & 7) ^ (l >> 3);         // logical chunk (0..7) -> k-offset lc*8
    facc acc[4][4];
    #pragma unroll
    for (int i = 0; i < 4; ++i)
        #pragma unroll
        for (int j = 0; j < 4; ++j) acc[i][j] = (facc)(0.0f);

    auto stage = [&](int buf, int e0) {
        #pragma unroll
        for (int i = 0; i < 4; ++i) {
            int slice = w * 4 + i;
            int row = slice * 8 + (l >> 3);
            gl_lds16(&att[(size_t)(rt * 128 + row) * 1024 + e0 + lc * 8], &Ab[buf][slice * 512]);
            gl_lds16(&WoB[(size_t)(ct * 128 + row) * 1024 + e0 + lc * 8], &Bb[buf][slice * 512]);
        }
    };

    stage(0, 0);
    int cur = 0;
    for (int t = 0; t < 16; ++t) {
        __syncthreads();
        if (t < 15) stage(cur ^ 1, (t + 1) * 64);
        __builtin_amdgcn_sched_barrier(0);
        __builtin_amdgcn_s_barrier();
        __builtin_amdgcn_sched_barrier(0);
        #pragma unroll
        for (int s = 0; s < 2; ++s) {
            const int slot = (s * 4 + (l >> 4)) ^ (l & 7);
            bfrag af[4], bf_[4];
            #pragma unroll
            for (int m = 0; m < 4; ++m)
                af[m] = *(const bfrag*)&Ab[cur][(wm * 64 + m * 16 + (l & 15)) * 64 + slot * 8];
            #pragma unroll
            for (int n = 0; n < 4; ++n)
                bf_[n] = *(const bfrag*)&Bb[cur][(wn * 64 + n * 16 + (l & 15)) * 64 + slot * 8];
            #pragma unroll
            for (int m = 0; m < 4; ++m)
                #pragma unroll
                for (int n = 0; n < 4; ++n)
                    acc[m][n] = MFMA(af[m], bf_[n], acc[m][n]);
        }
        cur ^= 1;
    }
    #pragma unroll
    for (int m = 0; m < 4; ++m)
        #pragma unroll
        for (int r = 0; r < 4; ++r) {
            int row = rt * 128 + wm * 64 + m * 16 + (l >> 4) * 4 + r;
            #pragma unroll
            for (int n = 0; n < 4; ++n) {
                int col = ct * 128 + wn * 64 + n * 16 + (l & 15);
                out[(size_t)row * 1024 + col] = acc[m][n][r];
            }
        }
}

// ---------------------------------------------------------------------------
extern "C" void kernel_launch(void* const* d_in, const int* in_sizes, int n_in,
                              void* d_out, int out_size, void* d_ws, size_t ws_size,
                              hipStream_t stream) {
    const float* x  = (const float*)d_in[0];
    // d_in[1]: causal mask (applied analytically)
    const float* Wq = (const float*)d_in[2];
    const float* Wk = (const float*)d_in[3];
    const float* Wv = (const float*)d_in[4];
    const float* Wo = (const float*)d_in[5];

    uint8_t* wsb = (uint8_t*)d_ws;
    const size_t MB = 1024 * 1024;
    // 64MB layout.  xh overlays att (xh dead before attn writes att).
    unsigned short* WqTh = (unsigned short*)(wsb + 0 * MB);
    unsigned short* WqTl = (unsigned short*)(wsb + 2 * MB);
    unsigned short* WkTh = (unsigned short*)(wsb + 4 * MB);
    unsigned short* WkTl = (unsigned short*)(wsb + 6 * MB);
    unsigned short* WvT  = (unsigned short*)(wsb + 8 * MB);
    unsigned short* qh   = (unsigned short*)(wsb + 10 * MB);  // 8MB
    unsigned char*  ql8  = (unsigned char*)(wsb + 18 * MB);   // 4MB fp8
    unsigned short* kh   = (unsigned short*)(wsb + 22 * MB);  // 8MB
    unsigned short* kl   = (unsigned short*)(wsb + 30 * MB);  // 8MB
    unsigned short* vT   = (unsigned short*)(wsb + 38 * MB);  // 8MB
    unsigned short* att  = (unsigned short*)(wsb + 46 * MB);  // 8MB
    unsigned short* xh   = (unsigned short*)(wsb + 46 * MB);  // 8MB (alias att)
    unsigned short* WoB  = (unsigned short*)(wsb + 54 * MB);  // 2MB
    unsigned short* xl   = (unsigned short*)(wsb + 56 * MB);  // 8MB

    hipFuncSetAttribute((const void*)qkv_fused,
                        hipFuncAttributeMaxDynamicSharedMemorySize, 73728);

    prep_all<<<dim3(5888), 256, 0, stream>>>(x, Wo, Wq, Wk, Wv, xh, xl, WoB,
                                             WqTh, WqTl, WkTh, WkTl, WvT);
    qkv_fused<<<dim3(16, 32), 256, 73728, stream>>>(xh, xl, WqTh, WqTl, WkTh, WkTl, WvT,
                                                    qh, ql8, kh, kl, vT);
    attn_mfma<<<dim3(32, 32), 256, 0, stream>>>(qh, ql8, kh, kl, vT, att);
    outproj<<<dim3(32, 8), 256, 0, stream>>>(att, WoB, (float*)d_out);
}

// Round 16
// 150.574 us; speedup vs baseline: 1.1056x; 1.0153x over previous
//
#include <hip/hip_runtime.h>
#include <hip/hip_fp8.h>
#include <stdint.h>

// (B,T,E,H,D) = (2,2048,1024,16,64)
constexpr float INV_SCALE = 0.022097086912079608f;  // 1/sqrt(2048)
constexpr float LOG2E = 1.4426950408889634f;
constexpr float QSC = INV_SCALE * LOG2E;            // q pre-scale: softmax in exp2 domain

typedef __attribute__((ext_vector_type(8))) short bfrag;          // 8 bf16 (4 VGPR) MFMA frag
typedef __attribute__((ext_vector_type(4))) float facc;           // 4 f32 MFMA acc
typedef __attribute__((ext_vector_type(4))) unsigned short us4;   // 4 bf16 = 8B

#define MFMA(a, b, c) __builtin_amdgcn_mfma_f32_16x16x32_bf16((a), (b), (c), 0, 0, 0)
#define EXP2(x) __builtin_amdgcn_exp2f(x)

__device__ __forceinline__ unsigned short f2bh(float f) {        // f32 -> bf16 RNE
    union { float f; unsigned int u; } cv; cv.f = f;
    unsigned int u = cv.u;
    u += 0x7FFFu + ((u >> 16) & 1u);
    return (unsigned short)(u >> 16);
}
__device__ __forceinline__ float bh2f(unsigned short h) {
    union { unsigned int u; float f; } cv; cv.u = ((unsigned int)h) << 16;
    return cv.f;
}
__device__ __forceinline__ void gl_lds16(const unsigned short* g, unsigned short* lds) {
    // async 16B/lane global->LDS; dst is wave-uniform base, lane i lands at dst+16*i
    __builtin_amdgcn_global_load_lds(
        (const __attribute__((address_space(1))) unsigned int*)g,
        (__attribute__((address_space(3))) unsigned int*)lds, 16, 0, 0);
}
// 8 fp8(e4m3, x256) bytes -> bf16 frag (undo the 256x scale)
__device__ __forceinline__ bfrag f8frag(uint2 raw) {
    union { uint2 u; unsigned char b[8]; } cv; cv.u = raw;
    bfrag r;
    #pragma unroll
    for (int j = 0; j < 8; ++j) {
        const __hip_fp8_e4m3* t = reinterpret_cast<const __hip_fp8_e4m3*>(&cv.b[j]);
        r[j] = (short)f2bh((float)(*t) * 0.00390625f);
    }
    return r;
}
// one DPP max-reduce stage over the 16-lane row (pure VALU, no LDS)
template<int CTRL>
__device__ __forceinline__ float dppmax(float v) {
    int s = __builtin_amdgcn_update_dpp(0, __builtin_bit_cast(int, v), CTRL, 0xF, 0xF, true);
    return fmaxf(v, __builtin_bit_cast(float, s));
}
__device__ __forceinline__ float rowmax16(float v) {
    v = dppmax<0xB1>(v);    // quad_perm [1,0,3,2]  (xor 1)
    v = dppmax<0x4E>(v);    // quad_perm [2,3,0,1]  (xor 2)
    v = dppmax<0x141>(v);   // row_half_mirror      (covers xor 4)
    v = dppmax<0x140>(v);   // row_mirror           (covers xor 8)
    return v;
}

// ---------------------------------------------------------------------------
// prep_all: ONE launch for all preprocessing.
//   blocks [0,768):    per-head transpose W{q,k,v} -> WT (hi/lo split)
//   blocks [768,1792):  Wo fp32 -> bf16
//   blocks [1792,5888): x fp32 -> hi/lo bf16 planes
// ---------------------------------------------------------------------------
__global__ __launch_bounds__(256) void prep_all(
    const float* __restrict__ x, const float* __restrict__ Wo,
    const float* __restrict__ Wq, const float* __restrict__ Wk, const float* __restrict__ Wv,
    unsigned short* __restrict__ xh, unsigned short* __restrict__ xl,
    unsigned short* __restrict__ WoB,
    unsigned short* __restrict__ WqTh, unsigned short* __restrict__ WqTl,
    unsigned short* __restrict__ WkTh, unsigned short* __restrict__ WkTl,
    unsigned short* __restrict__ WvT)
{
    __shared__ float tile[64][65];
    const int tid = threadIdx.x;
    const int bx = blockIdx.x;
    if (bx < 768) {
        const int et = bx & 15, h = (bx >> 4) & 15, m = bx >> 8;
        const float* W = (m == 0) ? Wq : (m == 1) ? Wk : Wv;
        #pragma unroll
        for (int rep = 0; rep < 4; ++rep) {
            int idx = rep * 256 + tid;            // f4 idx over [64e][16 i4]
            int e = idx >> 4, i4 = (idx & 15) * 4;
            facc v = *(const facc*)&W[(size_t)h * 65536 + (size_t)(et * 64 + e) * 64 + i4];
            tile[e][i4] = v.x; tile[e][i4 + 1] = v.y; tile[e][i4 + 2] = v.z; tile[e][i4 + 3] = v.w;
        }
        __syncthreads();
        unsigned short* Oh = (m == 0) ? WqTh : (m == 1) ? WkTh : WvT;
        unsigned short* Ol = (m == 0) ? WqTl : WkTl;
        #pragma unroll
        for (int rep = 0; rep < 4; ++rep) {
            int idx = rep * 256 + tid;            // [64 i][16 e4]
            int i = idx >> 4, e4 = (idx & 15) * 4;
            us4 hv, lv;
            #pragma unroll
            for (int j = 0; j < 4; ++j) {
                float f = tile[e4 + j][i];
                unsigned short hb = f2bh(f);
                hv[j] = hb;
                lv[j] = f2bh(f - bh2f(hb));
            }
            size_t o = (size_t)(h * 64 + i) * 1024 + et * 64 + e4;
            *(us4*)&Oh[o] = hv;
            if (m < 2) *(us4*)&Ol[o] = lv;
        }
    } else if (bx < 1792) {
        int idx = (bx - 768) * 256 + tid;         // f4 index, 262144 total
        facc v = *(const facc*)&Wo[(size_t)idx * 4];
        us4 o;
        #pragma unroll
        for (int j = 0; j < 4; ++j) o[j] = f2bh(v[j]);
        *(us4*)&WoB[(size_t)idx * 4] = o;
    } else {
        int idx = (bx - 1792) * 256 + tid;        // f4 idx, 1,048,576 total
        facc v = *(const facc*)&x[(size_t)idx * 4];
        us4 hv, lv;
        #pragma unroll
        for (int j = 0; j < 4; ++j) {
            unsigned short hb = f2bh(v[j]);
            hv[j] = hb;
            lv[j] = f2bh(v[j] - bh2f(hb));
        }
        *(us4*)&xh[(size_t)idx * 4] = hv;
        *(us4*)&xl[(size_t)idx * 4] = lv;
    }
}

// ---------------------------------------------------------------------------
// qkv_fused: block (ct, rt) computes q,k,v for rows [rt*128,+128), cols
// [ct*64,+64) in one K=1024 pass.  256 threads (4 waves, 2x2).
// 52KB static LDS -> 3 blocks/CU (three independent barrier domains).
// A (reused by q,k,v) double-buffered with cross-step prefetch; Q/K/V
// single-buffered JIT at step top (attn-R11 proven pattern): issue JIT 5
// loads then A-prefetch 4 loads, vmcnt(4) leaves only the A prefetch in
// flight.  grid (16 ct, 32 rt) = 512 blocks.
// ---------------------------------------------------------------------------
__global__ __launch_bounds__(256, 3) void qkv_fused(
    const unsigned short* __restrict__ xh, const unsigned short* __restrict__ xl,
    const unsigned short* __restrict__ WqTh, const unsigned short* __restrict__ WqTl,
    const unsigned short* __restrict__ WkTh, const unsigned short* __restrict__ WkTl,
    const unsigned short* __restrict__ WvT,
    unsigned short* __restrict__ qh, unsigned char* __restrict__ ql8,
    unsigned short* __restrict__ kh, unsigned short* __restrict__ kl,
    unsigned short* __restrict__ vT)
{
    __shared__ unsigned short Ab[2][8192];   // 32KB: x hi|lo packed, XOR-8 swz
    __shared__ unsigned short Qb[4096];      // 8KB (single, JIT)
    __shared__ unsigned short Kb[4096];      // 8KB (single, JIT)
    __shared__ unsigned short Vb[2048];      // 4KB (single, JIT; (row>>1)&3 swz)
    const int tid = threadIdx.x;
    const int w = tid >> 6, l = tid & 63;
    const int wm = w >> 1, wn = w & 1;       // 2 x 2 wave grid
    const int ct = blockIdx.x, rt = blockIdx.y;

    const int lc = (l & 7) ^ (l >> 3);       // logical chunk at dest (128B rows)
    const int krel = (lc & 3) * 8;
    const unsigned short* Axp = (lc < 4) ? xh : xl;
    const unsigned short* Qp  = (lc < 4) ? WqTh : WqTl;
    const unsigned short* Kp  = (lc < 4) ? WkTh : WkTl;
    const int lcv = (l & 3) ^ ((l >> 3) & 3);   // V logical chunk (64B rows)

    facc accq[4][2], acck[4][2], accv[4][2];
    #pragma unroll
    for (int m = 0; m < 4; ++m)
        #pragma unroll
        for (int n = 0; n < 2; ++n) {
            accq[m][n] = (facc)(0.0f); acck[m][n] = (facc)(0.0f); accv[m][n] = (facc)(0.0f);
        }

    auto stageA = [&](int buf, int e0) {
        #pragma unroll
        for (int i = 0; i < 4; ++i) {
            int slice = w * 4 + i;               // 0..15
            int row = slice * 8 + (l >> 3);
            gl_lds16(&Axp[(size_t)(rt * 128 + row) * 1024 + e0 + krel],
                     &Ab[buf][slice * 512]);
        }
    };
    auto stageQKV = [&](int e0) {
        #pragma unroll
        for (int i = 0; i < 2; ++i) {
            int slice = w * 2 + i;               // 0..7
            int row = slice * 8 + (l >> 3);
            size_t sb = (size_t)(ct * 64 + row) * 1024 + e0 + krel;
            gl_lds16(&Qp[sb], &Qb[slice * 512]);
            gl_lds16(&Kp[sb], &Kb[slice * 512]);
        }
        int row = w * 16 + (l >> 2);
        gl_lds16(&WvT[(size_t)(ct * 64 + row) * 1024 + e0 + lcv * 8], &Vb[w * 512]);
    };

    stageA(0, 0);                                // prologue: A(0) prefetch

    for (int t = 0; t < 32; ++t) {
        __syncthreads();                         // drains A(t) + prior JIT; WAR-safe
        stageQKV(t * 32);                        // JIT 5 loads
        __builtin_amdgcn_sched_barrier(0);
        if (t < 31) stageA((t + 1) & 1, (t + 1) * 32);   // prefetch 4 loads
        __builtin_amdgcn_sched_barrier(0);
        if (t < 31) asm volatile("s_waitcnt vmcnt(4)" ::: "memory");  // JIT landed
        else        asm volatile("s_waitcnt vmcnt(0)" ::: "memory");
        __builtin_amdgcn_sched_barrier(0);
        __builtin_amdgcn_s_barrier();            // all waves' JIT landed; A prefetch in flight
        __builtin_amdgcn_sched_barrier(0);

        const unsigned short* Ac = Ab[t & 1];
        const int ca = (l >> 4) ^ (l & 7);       // phys chunk of hi frag (128B rows)
        const int cb = ca ^ 4;                   // lo frag

        bfrag afh[4], afl[4];
        #pragma unroll
        for (int m = 0; m < 4; ++m) {
            int row = wm * 64 + m * 16 + (l & 15);
            afh[m] = *(const bfrag*)&Ac[row * 64 + ca * 8];
            afl[m] = *(const bfrag*)&Ac[row * 64 + cb * 8];
        }
        #pragma unroll
        for (int n = 0; n < 2; ++n) {
            int nr = wn * 32 + n * 16 + (l & 15);
            int cv = (l >> 4) ^ ((nr >> 1) & 3); // V phys chunk (64B rows)
            bfrag bv = *(const bfrag*)&Vb[nr * 32 + cv * 8];
            #pragma unroll
            for (int m = 0; m < 4; ++m) accv[m][n] = MFMA(afh[m], bv, accv[m][n]);
        }
        #pragma unroll
        for (int n = 0; n < 2; ++n) {
            int nr = wn * 32 + n * 16 + (l & 15);
            bfrag bh = *(const bfrag*)&Qb[nr * 64 + ca * 8];
            bfrag bl = *(const bfrag*)&Qb[nr * 64 + cb * 8];
            #pragma unroll
            for (int m = 0; m < 4; ++m) {
                accq[m][n] = MFMA(afh[m], bh, accq[m][n]);
                accq[m][n] = MFMA(afh[m], bl, accq[m][n]);
                accq[m][n] = MFMA(afl[m], bh, accq[m][n]);
            }
        }
        #pragma unroll
        for (int n = 0; n < 2; ++n) {
            int nr = wn * 32 + n * 16 + (l & 15);
            bfrag bh = *(const bfrag*)&Kb[nr * 64 + ca * 8];
            bfrag bl = *(const bfrag*)&Kb[nr * 64 + cb * 8];
            #pragma unroll
            for (int m = 0; m < 4; ++m) {
                acck[m][n] = MFMA(afh[m], bh, acck[m][n]);
                acck[m][n] = MFMA(afh[m], bl, acck[m][n]);
                acck[m][n] = MFMA(afl[m], bh, acck[m][n]);
            }
        }
    }

    // epilogue
    #pragma unroll
    for (int m = 0; m < 4; ++m)
        #pragma unroll
        for (int r = 0; r < 4; ++r) {
            int row = rt * 128 + wm * 64 + m * 16 + (l >> 4) * 4 + r;
            #pragma unroll
            for (int n = 0; n < 2; ++n) {
                int col = ct * 64 + wn * 32 + n * 16 + (l & 15);
                float fq = accq[m][n][r] * QSC;
                unsigned short hb = f2bh(fq);
                qh[(size_t)row * 1024 + col] = hb;
                __hip_fp8_e4m3 e((fq - bh2f(hb)) * 256.0f);
                ql8[(size_t)row * 1024 + col] = *reinterpret_cast<unsigned char*>(&e);
                float fk = acck[m][n][r];
                unsigned short kb = f2bh(fk);
                kh[(size_t)row * 1024 + col] = kb;
                kl[(size_t)row * 1024 + col] = f2bh(fk - bh2f(kb));
            }
        }
    // v: write transposed vT[(h*2+b)*64 + d][t], pack 4 consecutive t
    #pragma unroll
    for (int m = 0; m < 4; ++m) {
        int t0g = rt * 128 + wm * 64 + m * 16 + (l >> 4) * 4;
        int b_ = t0g >> 11, t0 = t0g & 2047;
        #pragma unroll
        for (int n = 0; n < 2; ++n) {
            int col = ct * 64 + wn * 32 + n * 16 + (l & 15);
            int h_ = col >> 6, d = col & 63;
            us4 pk;
            #pragma unroll
            for (int r = 0; r < 4; ++r) pk[r] = f2bh(accv[m][n][r]);
            *(us4*)&vT[((size_t)((h_ * 2 + b_) * 64 + d)) * 2048 + t0] = pk;
        }
    }
}

// ---------------------------------------------------------------------------
// attn helpers
// ---------------------------------------------------------------------------
__device__ __forceinline__ void stage_k(
    const unsigned short* __restrict__ kh, const unsigned short* __restrict__ kl,
    unsigned short* Khb, unsigned short* Klb, int w, int l, int b, int h, int kt)
{
    #pragma unroll
    for (int i = 0; i < 2; ++i) {
        int pbase = (w * 2 + i) * 1024;    // uniform 1KB slice base (bytes)
        int p = pbase + l * 16;
        int row = p >> 7, slot = (p >> 4) & 7;
        int chunk = slot ^ (row & 7);      // inverse-swizzled source chunk
        size_t srcK = (size_t)(b * 2048 + kt * 64 + row) * 1024 + h * 64 + chunk * 8;
        gl_lds16(&kh[srcK], &Khb[pbase >> 1]);
        gl_lds16(&kl[srcK], &Klb[pbase >> 1]);
    }
}
__device__ __forceinline__ void stage_v(
    const unsigned short* __restrict__ vT, unsigned short* Vtb,
    int w, int l, int b, int h, int kt)
{
    #pragma unroll
    for (int i = 0; i < 2; ++i) {
        int pbase = (w * 2 + i) * 1024;
        int p = pbase + l * 16;
        int row = p >> 7, slot = (p >> 4) & 7;
        int chunk = slot ^ (row & 7);
        size_t srcV = ((size_t)(h * 2 + b) * 64 + row) * 2048 + (size_t)kt * 64 + chunk * 8;
        gl_lds16(&vT[srcV], &Vtb[pbase >> 1]);
    }
}

// ---------------------------------------------------------------------------
// attn_mfma: de-paired single-tile flash attention (R11 structure -- best
// measured).  grid (32, 32) = 1024 blocks (one 64-row q-tile each), 4 waves,
// 48KB static LDS -> 3 blocks/CU.  qt-major DESCENDING dispatch order
// (longest blocks first) lets the HW scheduler backfill the causal imbalance.
// K hi/lo double-buffered (prefetch across raw barrier); V single-buffered
// just-in-time: staged at iter top, drained by counted vmcnt(4) + raw
// barrier before PV.
// ---------------------------------------------------------------------------
__global__ __launch_bounds__(256, 3) void attn_mfma(
    const unsigned short* __restrict__ qh, const unsigned char* __restrict__ ql8,
    const unsigned short* __restrict__ kh, const unsigned short* __restrict__ kl,
    const unsigned short* __restrict__ vT, unsigned short* __restrict__ att)
{
    __shared__ unsigned short Kh[2][4096], Kl[2][4096], Vt[4096], Pl[4096];
    const int tid = threadIdx.x, w = tid >> 6, l = tid & 63;
    // dd ascending = dispatch order.  qt-major descending; XCD-striped hb.
    const int dd = blockIdx.y * 32 + blockIdx.x;
    const int xcd = dd & 7, sl = dd >> 3;          // sl in 0..127
    const int qt = 31 - (sl >> 2);                 // first dispatched = qt 31
    const int hb = xcd * 4 + (sl & 3);             // 4 hb per XCD (K/V L2-resident)
    const int h = hb >> 1, b = hb & 1;

    bfrag ones;
    #pragma unroll
    for (int j = 0; j < 8; ++j) ones[j] = (short)0x3F80;   // bf16 1.0

    bfrag qfh[2], qfl[2];
    {
        const int qrow = qt * 64 + w * 16 + (l & 15);
        const size_t qoff = (size_t)(b * 2048 + qrow) * 1024 + h * 64 + (l >> 4) * 8;
        qfh[0] = *(const bfrag*)&qh[qoff];
        qfh[1] = *(const bfrag*)&qh[qoff + 32];
        qfl[0] = f8frag(*(const uint2*)&ql8[qoff]);
        qfl[1] = f8frag(*(const uint2*)&ql8[qoff + 32]);
    }

    facc O[4], Osum;
    float mrow[4];
    #pragma unroll
    for (int f = 0; f < 4; ++f) O[f] = (facc)(0.0f);
    Osum = (facc)(0.0f);
    #pragma unroll
    for (int r = 0; r < 4; ++r) mrow[r] = -1e30f;

    stage_k(kh, kl, Kh[0], Kl[0], w, l, b, h, 0);
    for (int kt = 0; kt <= qt; ++kt) {
        const int cur = kt & 1;
        __syncthreads();                   // drains prior loads; WAR on K^1 and Vt
        stage_v(vT, Vt, w, l, b, h, kt);   // just-in-time V (2 loads)
        if (kt < qt)
            stage_k(kh, kl, Kh[cur ^ 1], Kl[cur ^ 1], w, l, b, h, kt + 1);  // 4 loads
        __builtin_amdgcn_sched_barrier(0);
        __builtin_amdgcn_s_barrier();      // all waves past their drain -> K[cur] valid
        __builtin_amdgcn_sched_barrier(0);

        // ---- QK^T (split 3-term) ----
        facc S[4];
        #pragma unroll
        for (int f = 0; f < 4; ++f) S[f] = (facc)(0.0f);
        __builtin_amdgcn_s_setprio(1);
        #pragma unroll
        for (int s = 0; s < 2; ++s) {
            #pragma unroll
            for (int f = 0; f < 4; ++f) {
                int key = f * 16 + (l & 15);
                int ch = (s * 4 + (l >> 4)) ^ (key & 7);
                bfrag kbh = *(const bfrag*)&Kh[cur][key * 64 + ch * 8];
                bfrag kbl = *(const bfrag*)&Kl[cur][key * 64 + ch * 8];
                S[f] = MFMA(qfh[s], kbh, S[f]);
                S[f] = MFMA(qfh[s], kbl, S[f]);
                S[f] = MFMA(qfl[s], kbh, S[f]);
            }
        }
        __builtin_amdgcn_s_setprio(0);
        if (kt == qt) {                    // causal mask on diagonal tile
            #pragma unroll
            for (int f = 0; f < 4; ++f) {
                int keyl = f * 16 + (l & 15);
                #pragma unroll
                for (int r = 0; r < 4; ++r) {
                    int qls = w * 16 + (l >> 4) * 4 + r;
                    if (keyl > qls) S[f][r] = -1e30f;
                }
            }
        }
        // ---- softmax: DPP row-max, defer-max (THR=8), exp2 ----
        float mx[4];
        float dmax = -3.0e38f;
        #pragma unroll
        for (int r = 0; r < 4; ++r) {
            float m0 = fmaxf(fmaxf(S[0][r], S[1][r]), fmaxf(S[2][r], S[3][r]));
            m0 = rowmax16(m0);
            mx[r] = m0;
            dmax = fmaxf(dmax, m0 - mrow[r]);
        }
        if (!__all(dmax <= 8.0f)) {        // wave-uniform, rare after warmup
            #pragma unroll
            for (int r = 0; r < 4; ++r) {
                float mn = fmaxf(mrow[r], mx[r]);
                float fac = EXP2(mrow[r] - mn);
                mrow[r] = mn;
                O[0][r] *= fac; O[1][r] *= fac; O[2][r] *= fac; O[3][r] *= fac;
                Osum[r] *= fac;
            }
        }
        #pragma unroll
        for (int r = 0; r < 4; ++r)
            #pragma unroll
            for (int f = 0; f < 4; ++f) S[f][r] = EXP2(S[f][r] - mrow[r]);
        // P -> LDS (bf16, swizzled rows; same-wave rows only)
        #pragma unroll
        for (int f = 0; f < 4; ++f) {
            int key = f * 16 + (l & 15);
            #pragma unroll
            for (int r = 0; r < 4; ++r) {
                int qr = w * 16 + (l >> 4) * 4 + r;
                Pl[qr * 64 + (((key >> 3) ^ (qr & 7)) * 8) + (key & 7)] = f2bh(S[f][r]);
            }
        }
        // ---- drain my V loads (K prefetch stays in flight), then sync ----
        __builtin_amdgcn_sched_barrier(0);
        if (kt < qt) asm volatile("s_waitcnt vmcnt(4)" ::: "memory");
        else         asm volatile("s_waitcnt vmcnt(0)" ::: "memory");
        __builtin_amdgcn_sched_barrier(0);
        __builtin_amdgcn_s_barrier();      // every wave's V landed -> Vt valid
        __builtin_amdgcn_sched_barrier(0);
        // ---- PV + denominator via ones-MFMA ----
        __builtin_amdgcn_s_setprio(1);
        #pragma unroll
        for (int s = 0; s < 2; ++s) {
            int qa = w * 16 + (l & 15);
            int cha = (s * 4 + (l >> 4)) ^ (qa & 7);
            bfrag pa = *(const bfrag*)&Pl[qa * 64 + cha * 8];
            Osum = MFMA(pa, ones, Osum);
            #pragma unroll
            for (int f = 0; f < 4; ++f) {
                int d = f * 16 + (l & 15);
                int chv = (s * 4 + (l >> 4)) ^ (d & 7);
                bfrag vb = *(const bfrag*)&Vt[d * 64 + chv * 8];
                O[f] = MFMA(pa, vb, O[f]);
            }
        }
        __builtin_amdgcn_s_setprio(0);
    }

    #pragma unroll
    for (int f = 0; f < 4; ++f) {
        int d = h * 64 + f * 16 + (l & 15);
        #pragma unroll
        for (int r = 0; r < 4; ++r) {
            int t = qt * 64 + w * 16 + (l >> 4) * 4 + r;
            att[(size_t)(b * 2048 + t) * 1024 + d] = f2bh(O[f][r] / Osum[r]);
        }
    }
}

// ---------------------------------------------------------------------------
// outproj: out[4096,1024] = att @ Wo^T.  BK=64 swizzled, double-buffered with
// the prefetch-across-raw-barrier loop.  grid (32, 8), 64KB LDS.
// ---------------------------------------------------------------------------
__global__ __launch_bounds__(256, 2) void outproj(
    const unsigned short* __restrict__ att, const unsigned short* __restrict__ WoB,
    float* __restrict__ out)
{
    __shared__ unsigned short Ab[2][128 * 64], Bb[2][128 * 64];
    const int tid = threadIdx.x, w = tid >> 6, l = tid & 63;
    const int wm = w >> 1, wn = w & 1;
    const int rt = blockIdx.x, ct = blockIdx.y;

    const int lc = (l & 7) ^ (l >> 3);         // logical chunk (0..7) -> k-offset lc*8
    facc acc[4][4];
    #pragma unroll
    for (int i = 0; i < 4; ++i)
        #pragma unroll
        for (int j = 0; j < 4; ++j) acc[i][j] = (facc)(0.0f);

    auto stage = [&](int buf, int e0) {
        #pragma unroll
        for (int i = 0; i < 4; ++i) {
            int slice = w * 4 + i;
            int row = slice * 8 + (l >> 3);
            gl_lds16(&att[(size_t)(rt * 128 + row) * 1024 + e0 + lc * 8], &Ab[buf][slice * 512]);
            gl_lds16(&WoB[(size_t)(ct * 128 + row) * 1024 + e0 + lc * 8], &Bb[buf][slice * 512]);
        }
    };

    stage(0, 0);
    int cur = 0;
    for (int t = 0; t < 16; ++t) {
        __syncthreads();
        if (t < 15) stage(cur ^ 1, (t + 1) * 64);
        __builtin_amdgcn_sched_barrier(0);
        __builtin_amdgcn_s_barrier();
        __builtin_amdgcn_sched_barrier(0);
        #pragma unroll
        for (int s = 0; s < 2; ++s) {
            const int slot = (s * 4 + (l >> 4)) ^ (l & 7);
            bfrag af[4], bf_[4];
            #pragma unroll
            for (int m = 0; m < 4; ++m)
                af[m] = *(const bfrag*)&Ab[cur][(wm * 64 + m * 16 + (l & 15)) * 64 + slot * 8];
            #pragma unroll
            for (int n = 0; n < 4; ++n)
                bf_[n] = *(const bfrag*)&Bb[cur][(wn * 64 + n * 16 + (l & 15)) * 64 + slot * 8];
            #pragma unroll
            for (int m = 0; m < 4; ++m)
                #pragma unroll
                for (int n = 0; n < 4; ++n)
                    acc[m][n] = MFMA(af[m], bf_[n], acc[m][n]);
        }
        cur ^= 1;
    }
    #pragma unroll
    for (int m = 0; m < 4; ++m)
        #pragma unroll
        for (int r = 0; r < 4; ++r) {
            int row = rt * 128 + wm * 64 + m * 16 + (l >> 4) * 4 + r;
            #pragma unroll
            for (int n = 0; n < 4; ++n) {
                int col = ct * 128 + wn * 64 + n * 16 + (l & 15);
                out[(size_t)row * 1024 + col] = acc[m][n][r];
            }
        }
}

// ---------------------------------------------------------------------------
extern "C" void kernel_launch(void* const* d_in, const int* in_sizes, int n_in,
                              void* d_out, int out_size, void* d_ws, size_t ws_size,
                              hipStream_t stream) {
    const float* x  = (const float*)d_in[0];
    // d_in[1]: causal mask (applied analytically)
    const float* Wq = (const float*)d_in[2];
    const float* Wk = (const float*)d_in[3];
    const float* Wv = (const float*)d_in[4];
    const float* Wo = (const float*)d_in[5];

    uint8_t* wsb = (uint8_t*)d_ws;
    const size_t MB = 1024 * 1024;
    // 64MB layout.  xh overlays att (xh dead before attn writes att).
    unsigned short* WqTh = (unsigned short*)(wsb + 0 * MB);
    unsigned short* WqTl = (unsigned short*)(wsb + 2 * MB);
    unsigned short* WkTh = (unsigned short*)(wsb + 4 * MB);
    unsigned short* WkTl = (unsigned short*)(wsb + 6 * MB);
    unsigned short* WvT  = (unsigned short*)(wsb + 8 * MB);
    unsigned short* qh   = (unsigned short*)(wsb + 10 * MB);  // 8MB
    unsigned char*  ql8  = (unsigned char*)(wsb + 18 * MB);   // 4MB fp8
    unsigned short* kh   = (unsigned short*)(wsb + 22 * MB);  // 8MB
    unsigned short* kl   = (unsigned short*)(wsb + 30 * MB);  // 8MB
    unsigned short* vT   = (unsigned short*)(wsb + 38 * MB);  // 8MB
    unsigned short* att  = (unsigned short*)(wsb + 46 * MB);  // 8MB
    unsigned short* xh   = (unsigned short*)(wsb + 46 * MB);  // 8MB (alias att)
    unsigned short* WoB  = (unsigned short*)(wsb + 54 * MB);  // 2MB
    unsigned short* xl   = (unsigned short*)(wsb + 56 * MB);  // 8MB

    prep_all<<<dim3(5888), 256, 0, stream>>>(x, Wo, Wq, Wk, Wv, xh, xl, WoB,
                                             WqTh, WqTl, WkTh, WkTl, WvT);
    qkv_fused<<<dim3(16, 32), 256, 0, stream>>>(xh, xl, WqTh, WqTl, WkTh, WkTl, WvT,
                                                qh, ql8, kh, kl, vT);
    attn_mfma<<<dim3(32, 32), 256, 0, stream>>>(qh, ql8, kh, kl, vT, att);
    outproj<<<dim3(32, 8), 256, 0, stream>>>(att, WoB, (float*)d_out);
}